// Round 1
// baseline (136.266 us; speedup 1.0000x reference)
//
#include <hip/hip_runtime.h>

// Problem constants (from reference)
#define BB   4
#define N1   1024
#define DIM  1024
#define FF   4
#define NN   1025           // N1 + 1
#define NTOT (FF * NN)      // 4100
#define SIM_TOTAL ((size_t)BB * N1 * NTOT)   // 16,793,600 floats
#define NEGV (-1e9f)

// ---------------------------------------------------------------------------
// Kernel 1: pure -1e9 fill of the sim region (write-only stream).
// SIM_TOTAL = 16,793,600 floats = 4,198,400 float4 (16B-aligned, divisible).
// Grid-stride float4 stores — the same pattern fillBufferAligned runs at
// ~6.5 TB/s on this chip.
// ---------------------------------------------------------------------------
__global__ __launch_bounds__(256)
void fill_neg_kernel(float4* __restrict__ out4) {
    const int n4 = (int)(SIM_TOTAL / 4);   // 4,198,400
    const float4 negv = make_float4(NEGV, NEGV, NEGV, NEGV);
    int idx = blockIdx.x * 256 + threadIdx.x;
    const int stride = gridDim.x * 256;
    for (; idx < n4; idx += stride)
        out4[idx] = negv;
}

// ---------------------------------------------------------------------------
// Kernel 2: read-only streaming compute + tiny scatter.
// One block (256 threads) per output row (b, i):
//  - load lhs row (1024 f32) as float4, accumulate |l|^2 partial
//  - for each f in 0..3: load rhs row (b, f*NN + i + 1), accumulate dot & |r|^2
//  - block-reduce 9 scalars, thread 0 overwrites the 4 kept sims + lhs_norm
// Runs strictly after the fill (same stream), so its scatter wins.
// ---------------------------------------------------------------------------
__device__ __forceinline__ float wave_reduce_sum(float v) {
#pragma unroll
    for (int off = 32; off > 0; off >>= 1)
        v += __shfl_down(v, off, 64);
    return v;
}

__global__ __launch_bounds__(256)
void compute_kernel(const float* __restrict__ lhs,
                    const float* __restrict__ rhs,
                    float* __restrict__ out) {
    const int row = blockIdx.x;        // 0 .. B*N1-1
    const int b   = row >> 10;         // / N1
    const int i   = row & (N1 - 1);    // % N1
    const int tid = threadIdx.x;

    // ---- lhs row load (256 threads x float4 = 1024 floats) ----
    const float4* lrow = (const float4*)(lhs + (size_t)row * DIM);
    const float4 lv = lrow[tid];
    float p_l2 = lv.x * lv.x + lv.y * lv.y + lv.z * lv.z + lv.w * lv.w;

    // ---- rhs rows: f*NN + i + 1 for f in 0..3 (independent loads) ----
    float p_dot[FF], p_r2[FF];
#pragma unroll
    for (int f = 0; f < FF; ++f) {
        const size_t rrow_idx = (size_t)b * NTOT + (size_t)f * NN + (i + 1);
        const float4* rrow = (const float4*)(rhs + rrow_idx * DIM);
        const float4 rv = rrow[tid];
        p_dot[f] = lv.x * rv.x + lv.y * rv.y + lv.z * rv.z + lv.w * rv.w;
        p_r2[f]  = rv.x * rv.x + rv.y * rv.y + rv.z * rv.z + rv.w * rv.w;
    }

    // ---- block reduction of 9 scalars ----
    float vals[9];
    vals[0] = p_l2;
#pragma unroll
    for (int f = 0; f < FF; ++f) {
        vals[1 + 2 * f] = p_dot[f];
        vals[2 + 2 * f] = p_r2[f];
    }

    __shared__ float red[4][9];
    const int wave = tid >> 6;
    const int lane = tid & 63;
#pragma unroll
    for (int q = 0; q < 9; ++q) {
        const float r = wave_reduce_sum(vals[q]);
        if (lane == 0) red[wave][q] = r;
    }
    __syncthreads();

    if (tid == 0) {
        float s[9];
#pragma unroll
        for (int q = 0; q < 9; ++q)
            s[q] = red[0][q] + red[1][q] + red[2][q] + red[3][q];

        const float l2 = s[0];
        float* orow = out + (size_t)row * NTOT;
#pragma unroll
        for (int f = 0; f < FF; ++f) {
            const float dot = s[1 + 2 * f];
            const float r2  = s[2 + 2 * f];
            orow[f * NN + i + 1] = (dot * dot) / (l2 * r2);
        }
        out[SIM_TOTAL + row] = sqrtf(l2);   // lhs_norm (B, N1, 1)
    }
}

extern "C" void kernel_launch(void* const* d_in, const int* in_sizes, int n_in,
                              void* d_out, int out_size, void* d_ws, size_t ws_size,
                              hipStream_t stream) {
    const float* lhs = (const float*)d_in[0];  // (B, N1, DIM)
    const float* rhs = (const float*)d_in[1];  // (B, NTOT, DIM)
    float* out = (float*)d_out;                // sim (B,N1,NTOT) ++ lhs_norm (B,N1,1)

    // Write-only stream: fill sim region with -1e9 at pure-store bandwidth.
    fill_neg_kernel<<<2048, 256, 0, stream>>>((float4*)out);

    // Read-only stream + tiny scatter (stream-ordered after the fill).
    compute_kernel<<<BB * N1, 256, 0, stream>>>(lhs, rhs, out);
}

// Round 2
// 129.257 us; speedup vs baseline: 1.0542x; 1.0542x over previous
//
#include <hip/hip_runtime.h>

// Problem constants (from reference)
#define BB   4
#define N1   1024
#define DIM  1024
#define FF   4
#define NN   1025           // N1 + 1
#define NTOT (FF * NN)      // 4100
#define SIM_TOTAL ((size_t)BB * N1 * NTOT)   // 16,793,600 floats
#define NEGV (-1e9f)

// ext_vector float4 so __builtin_nontemporal_* accepts it
typedef float f4 __attribute__((ext_vector_type(4)));

__device__ __forceinline__ f4 nt_load(const f4* p)  { return __builtin_nontemporal_load(p); }
__device__ __forceinline__ void nt_store(f4* p, f4 v) { __builtin_nontemporal_store(v, p); }

// One WAVE (64 lanes) per output row (b, i). 4 waves / 256-thread block.
//  - issue the row's 17 nt fill-stores first (write stream starts immediately)
//  - 64 lanes x 4 float4 = lhs row; 4 rhs rows likewise (nt loads, zero reuse)
//  - 9-value wave butterfly reduce (__shfl_xor) — no LDS, no __syncthreads
//  - s_waitcnt vmcnt(0) (wave-local) orders fill WAW against lane-0 scatter
__global__ __launch_bounds__(256)
void lcs_kernel(const float* __restrict__ lhs,
                const float* __restrict__ rhs,
                float* __restrict__ out) {
    const int lane = threadIdx.x & 63;
    const int row  = (blockIdx.x << 2) | (threadIdx.x >> 6);   // 0 .. B*N1-1
    const int b    = row >> 10;         // / N1
    const int i    = row & (N1 - 1);    // % N1

    // ---- fill stores first: 1025 float4 per row, 16/lane + lane-0 tail ----
    f4* orow4 = (f4*)(out + (size_t)row * NTOT);
    const f4 negv = { NEGV, NEGV, NEGV, NEGV };
#pragma unroll
    for (int c = 0; c < 16; ++c)
        nt_store(orow4 + lane + 64 * c, negv);
    if (lane == 0)
        nt_store(orow4 + 1024, negv);

    // ---- lhs row: 64 lanes x 4 float4 = 1024 floats ----
    const f4* lrow = (const f4*)(lhs + (size_t)row * DIM);
    f4 lv[4];
#pragma unroll
    for (int c = 0; c < 4; ++c)
        lv[c] = nt_load(lrow + lane + 64 * c);

    float l2 = 0.f;
#pragma unroll
    for (int c = 0; c < 4; ++c)
        l2 += lv[c].x * lv[c].x + lv[c].y * lv[c].y
            + lv[c].z * lv[c].z + lv[c].w * lv[c].w;

    // ---- rhs rows f*NN + i + 1, f = 0..3 ----
    float dot[FF], r2[FF];
#pragma unroll
    for (int f = 0; f < FF; ++f) {
        const size_t rrow_idx = (size_t)b * NTOT + (size_t)f * NN + (i + 1);
        const f4* rrow = (const f4*)(rhs + rrow_idx * DIM);
        float d = 0.f, r = 0.f;
#pragma unroll
        for (int c = 0; c < 4; ++c) {
            const f4 rv = nt_load(rrow + lane + 64 * c);
            d += lv[c].x * rv.x + lv[c].y * rv.y + lv[c].z * rv.z + lv[c].w * rv.w;
            r += rv.x * rv.x + rv.y * rv.y + rv.z * rv.z + rv.w * rv.w;
        }
        dot[f] = d;
        r2[f]  = r;
    }

    // ---- wave butterfly reduce: 9 scalars x 6 steps ----
    float vals[9];
    vals[0] = l2;
#pragma unroll
    for (int f = 0; f < FF; ++f) {
        vals[1 + 2 * f] = dot[f];
        vals[2 + 2 * f] = r2[f];
    }
#pragma unroll
    for (int q = 0; q < 9; ++q) {
#pragma unroll
        for (int off = 32; off > 0; off >>= 1)
            vals[q] += __shfl_xor(vals[q], off, 64);
    }

    // ---- drain fill stores (wave-local), then lane 0 scatters results ----
    asm volatile("s_waitcnt vmcnt(0)" ::: "memory");
    if (lane == 0) {
        const float l2s = vals[0];
        float* orow = out + (size_t)row * NTOT;
#pragma unroll
        for (int f = 0; f < FF; ++f) {
            const float d = vals[1 + 2 * f];
            const float r = vals[2 + 2 * f];
            orow[f * NN + i + 1] = (d * d) / (l2s * r);
        }
        out[SIM_TOTAL + row] = sqrtf(l2s);   // lhs_norm (B, N1, 1)
    }
}

extern "C" void kernel_launch(void* const* d_in, const int* in_sizes, int n_in,
                              void* d_out, int out_size, void* d_ws, size_t ws_size,
                              hipStream_t stream) {
    const float* lhs = (const float*)d_in[0];  // (B, N1, DIM)
    const float* rhs = (const float*)d_in[1];  // (B, NTOT, DIM)
    float* out = (float*)d_out;                // sim (B,N1,NTOT) ++ lhs_norm (B,N1,1)

    lcs_kernel<<<BB * N1 / 4, 256, 0, stream>>>(lhs, rhs, out);
}

// Round 3
// 128.955 us; speedup vs baseline: 1.0567x; 1.0023x over previous
//
#include <hip/hip_runtime.h>

// Problem constants (from reference)
#define BB   4
#define N1   1024
#define DIM  1024
#define FF   4
#define NN   1025           // N1 + 1
#define NTOT (FF * NN)      // 4100
#define SIM_TOTAL ((size_t)BB * N1 * NTOT)   // 16,793,600 floats
#define NEGV (-1e9f)

typedef float f4 __attribute__((ext_vector_type(4)));

// One WAVE per output row, TWO rows per wave (r and r+2048), no LDS, no
// barriers, no waitcnt games:
//  - all 40 float4 loads (both rows) issue up front; row-1 HBM latency
//    hides under row-0's FMA + butterfly reduce
//  - the -1e9 fill SKIPS the 4 float4 slots that will hold results
//    (per-lane 17-bit skip mask) -> no WAW hazard, no ordering needed
//  - butterfly reduce leaves all 9 sums in every lane; the lanes that own
//    the special float4 slots compose (3x NEG + sim) with compile-time
//    selects and store them -> no serialized lane-0 epilogue
__global__ __launch_bounds__(256, 2)
void lcs_kernel(const float* __restrict__ lhs,
                const float* __restrict__ rhs,
                float* __restrict__ out) {
    const int lane = threadIdx.x & 63;
    const int w    = (blockIdx.x << 2) | (threadIdx.x >> 6);   // 0 .. 2047

    int rows[2];
    rows[0] = w;
    rows[1] = w + 2048;

    // ---- issue ALL loads for both rows (scheduler may re-balance) ----
    f4 lv[2][4];
    f4 rv[2][FF][4];
#pragma unroll
    for (int t = 0; t < 2; ++t) {
        const int row = rows[t];
        const int b   = row >> 10;
        const int i   = row & (N1 - 1);
        const f4* lrow = (const f4*)(lhs + (size_t)row * DIM);
#pragma unroll
        for (int c = 0; c < 4; ++c)
            lv[t][c] = lrow[lane + 64 * c];
#pragma unroll
        for (int f = 0; f < FF; ++f) {
            const f4* rrow =
                (const f4*)(rhs + ((size_t)b * NTOT + (size_t)f * NN + (i + 1)) * DIM);
#pragma unroll
            for (int c = 0; c < 4; ++c)
                rv[t][f][c] = rrow[lane + 64 * c];
        }
    }

    // ---- per-row special-slot bookkeeping (result positions) ----
    int kf[2][FF], mf[2][FF];
    unsigned smask[2];                // bits 0..16 over fill chunks c
#pragma unroll
    for (int t = 0; t < 2; ++t) {
        const int i = rows[t] & (N1 - 1);
        unsigned m = 0;
#pragma unroll
        for (int f = 0; f < FF; ++f) {
            const int j = f * NN + i + 1;       // kept column, 1..4099
            kf[t][f] = j >> 2;                  // float4 slot, 0..1024
            mf[t][f] = j & 3;                   // component
            if ((kf[t][f] & 63) == lane)
                m |= 1u << (kf[t][f] >> 6);
        }
        smask[t] = m;
    }

    // ---- fill both rows with -1e9, skipping the 4 special slots ----
    const f4 negv = { NEGV, NEGV, NEGV, NEGV };
#pragma unroll
    for (int t = 0; t < 2; ++t) {
        f4* orow4 = (f4*)(out + (size_t)rows[t] * NTOT);
#pragma unroll
        for (int c = 0; c < 16; ++c)
            if (!((smask[t] >> c) & 1))
                orow4[lane + 64 * c] = negv;
        if (lane == 0 && !((smask[t] >> 16) & 1))
            orow4[1024] = negv;                 // tail slot (j = 4096..4099)
    }

    // ---- per row: FMA, butterfly reduce, special-slot stores ----
#pragma unroll
    for (int t = 0; t < 2; ++t) {
        float vals[9];
        float l2 = 0.f;
#pragma unroll
        for (int c = 0; c < 4; ++c)
            l2 += lv[t][c].x * lv[t][c].x + lv[t][c].y * lv[t][c].y
                + lv[t][c].z * lv[t][c].z + lv[t][c].w * lv[t][c].w;
        vals[0] = l2;
#pragma unroll
        for (int f = 0; f < FF; ++f) {
            float d = 0.f, r = 0.f;
#pragma unroll
            for (int c = 0; c < 4; ++c) {
                const f4 a = lv[t][c], bz = rv[t][f][c];
                d += a.x * bz.x + a.y * bz.y + a.z * bz.z + a.w * bz.w;
                r += bz.x * bz.x + bz.y * bz.y + bz.z * bz.z + bz.w * bz.w;
            }
            vals[1 + 2 * f] = d;
            vals[2 + 2 * f] = r;
        }

#pragma unroll
        for (int q = 0; q < 9; ++q) {
#pragma unroll
            for (int off = 32; off > 0; off >>= 1)
                vals[q] += __shfl_xor(vals[q], off, 64);
        }

        const float l2s = vals[0];
        f4* orow4 = (f4*)(out + (size_t)rows[t] * NTOT);
#pragma unroll
        for (int f = 0; f < FF; ++f) {
            if ((kf[t][f] & 63) == lane) {
                const float d   = vals[1 + 2 * f];
                const float r   = vals[2 + 2 * f];
                const float sim = (d * d) / (l2s * r);
                f4 v;
                v.x = (mf[t][f] == 0) ? sim : NEGV;
                v.y = (mf[t][f] == 1) ? sim : NEGV;
                v.z = (mf[t][f] == 2) ? sim : NEGV;
                v.w = (mf[t][f] == 3) ? sim : NEGV;
                orow4[kf[t][f]] = v;
            }
        }
        if (lane == 0)
            out[SIM_TOTAL + rows[t]] = sqrtf(l2s);   // lhs_norm (B, N1, 1)
    }
}

extern "C" void kernel_launch(void* const* d_in, const int* in_sizes, int n_in,
                              void* d_out, int out_size, void* d_ws, size_t ws_size,
                              hipStream_t stream) {
    const float* lhs = (const float*)d_in[0];  // (B, N1, DIM)
    const float* rhs = (const float*)d_in[1];  // (B, NTOT, DIM)
    float* out = (float*)d_out;                // sim (B,N1,NTOT) ++ lhs_norm (B,N1,1)

    // 512 blocks x 4 waves = 2048 waves; 2 rows per wave = 4096 rows.
    lcs_kernel<<<512, 256, 0, stream>>>(lhs, rhs, out);
}

// Round 4
// 126.266 us; speedup vs baseline: 1.0792x; 1.0213x over previous
//
#include <hip/hip_runtime.h>

// Problem constants (from reference)
#define BB   4
#define N1   1024
#define DIM  1024
#define FF   4
#define NN   1025           // N1 + 1
#define NTOT (FF * NN)      // 4100
#define SIM_TOTAL ((size_t)BB * N1 * NTOT)   // 16,793,600 floats
#define NEGV (-1e9f)

typedef float f4 __attribute__((ext_vector_type(4)));

// One WAVE per output row. Clean configuration isolating the wins from R2/R3
// without their regressions:
//  - PLAIN cached loads (no nontemporal — R2 showed nt hurt)
//  - loads issued FIRST (latency starts earliest; fill stores never stall)
//  - fill SKIPS the 4 result slots (per-lane 17-bit mask) -> no WAW hazard,
//    no s_waitcnt, no LDS, no barrier anywhere
//  - butterfly reduce leaves all 9 sums in every lane; owner lanes compose
//    (3x NEG + sim) f4s and store -> no serialized lane-0 epilogue
//  - no launch_bounds occupancy cap: ~20 live f4 -> ~120 VGPR -> 4 waves/SIMD,
//    entire grid (4096 waves) resident in one generation
__global__ __launch_bounds__(256)
void lcs_kernel(const float* __restrict__ lhs,
                const float* __restrict__ rhs,
                float* __restrict__ out) {
    const int lane = threadIdx.x & 63;
    const int row  = (blockIdx.x << 2) | (threadIdx.x >> 6);   // 0 .. B*N1-1
    const int b    = row >> 10;         // / N1
    const int i    = row & (N1 - 1);    // % N1

    // ---- issue all 20 loads first (plain, cached) ----
    const f4* lrow = (const f4*)(lhs + (size_t)row * DIM);
    f4 lv[4];
#pragma unroll
    for (int c = 0; c < 4; ++c)
        lv[c] = lrow[lane + 64 * c];

    f4 rv[FF][4];
#pragma unroll
    for (int f = 0; f < FF; ++f) {
        const f4* rrow =
            (const f4*)(rhs + ((size_t)b * NTOT + (size_t)f * NN + (i + 1)) * DIM);
#pragma unroll
        for (int c = 0; c < 4; ++c)
            rv[f][c] = rrow[lane + 64 * c];
    }

    // ---- result-slot bookkeeping ----
    int kf[FF], mf[FF];
    unsigned smask = 0;                 // bits 0..16 over fill chunks
#pragma unroll
    for (int f = 0; f < FF; ++f) {
        const int j = f * NN + i + 1;   // kept column, 1..4099
        kf[f] = j >> 2;                 // float4 slot, 0..1024
        mf[f] = j & 3;                  // component within slot
        if ((kf[f] & 63) == lane)
            smask |= 1u << (kf[f] >> 6);
    }

    // ---- fill row with -1e9, skipping result slots (stores don't stall) ----
    f4* orow4 = (f4*)(out + (size_t)row * NTOT);
    const f4 negv = { NEGV, NEGV, NEGV, NEGV };
#pragma unroll
    for (int c = 0; c < 16; ++c)
        if (!((smask >> c) & 1))
            orow4[lane + 64 * c] = negv;
    if (lane == 0 && !((smask >> 16) & 1))
        orow4[1024] = negv;             // tail slot (columns 4096..4099)

    // ---- partials ----
    float vals[9];
    {
        float l2 = 0.f;
#pragma unroll
        for (int c = 0; c < 4; ++c)
            l2 += lv[c].x * lv[c].x + lv[c].y * lv[c].y
                + lv[c].z * lv[c].z + lv[c].w * lv[c].w;
        vals[0] = l2;
    }
#pragma unroll
    for (int f = 0; f < FF; ++f) {
        float d = 0.f, r = 0.f;
#pragma unroll
        for (int c = 0; c < 4; ++c) {
            const f4 a = lv[c], z = rv[f][c];
            d += a.x * z.x + a.y * z.y + a.z * z.z + a.w * z.w;
            r += z.x * z.x + z.y * z.y + z.z * z.z + z.w * z.w;
        }
        vals[1 + 2 * f] = d;
        vals[2 + 2 * f] = r;
    }

    // ---- wave butterfly reduce: 9 independent chains x 6 steps ----
#pragma unroll
    for (int q = 0; q < 9; ++q) {
#pragma unroll
        for (int off = 32; off > 0; off >>= 1)
            vals[q] += __shfl_xor(vals[q], off, 64);
    }

    // ---- owner lanes store composed result slots; lane 0 stores norm ----
    const float l2s = vals[0];
#pragma unroll
    for (int f = 0; f < FF; ++f) {
        if ((kf[f] & 63) == lane) {
            const float d   = vals[1 + 2 * f];
            const float r   = vals[2 + 2 * f];
            const float sim = (d * d) / (l2s * r);
            f4 v;
            v.x = (mf[f] == 0) ? sim : NEGV;
            v.y = (mf[f] == 1) ? sim : NEGV;
            v.z = (mf[f] == 2) ? sim : NEGV;
            v.w = (mf[f] == 3) ? sim : NEGV;
            orow4[kf[f]] = v;
        }
    }
    if (lane == 0)
        out[SIM_TOTAL + row] = sqrtf(l2s);   // lhs_norm (B, N1, 1)
}

extern "C" void kernel_launch(void* const* d_in, const int* in_sizes, int n_in,
                              void* d_out, int out_size, void* d_ws, size_t ws_size,
                              hipStream_t stream) {
    const float* lhs = (const float*)d_in[0];  // (B, N1, DIM)
    const float* rhs = (const float*)d_in[1];  // (B, NTOT, DIM)
    float* out = (float*)d_out;                // sim (B,N1,NTOT) ++ lhs_norm (B,N1,1)

    // 1024 blocks x 4 waves = 4096 waves, one per row, single generation.
    lcs_kernel<<<BB * N1 / 4, 256, 0, stream>>>(lhs, rhs, out);
}